// Round 3
// baseline (802.912 us; speedup 1.0000x reference)
//
#include <hip/hip_runtime.h>

// Problem constants (fixed by setup_inputs): B=2, C=32, H=128, W=240, D=48.
constexpr int B  = 2;
constexpr int C  = 32;
constexpr int H  = 128;
constexpr int W  = 240;
constexpr int D  = 48;
constexpr int W4 = W / 4;                                   // 60 float4 per row
constexpr int TOT4 = B * (2 * C) * D * H * W4;              // 47,185,920 (< 2^31)

// clang-native vector type: accepted by __builtin_nontemporal_store
// (HIP's float4 is a struct and is rejected).
typedef float f32x4 __attribute__((ext_vector_type(4)));

__global__ __launch_bounds__(256) void concat_volume_kernel(
    const float* __restrict__ L,
    const float* __restrict__ R,
    float* __restrict__ out)
{
    const int stride = gridDim.x * blockDim.x;
    for (int o = blockIdx.x * blockDim.x + threadIdx.x; o < TOT4; o += stride) {
        // Decompose o -> (b, cc, d, h, w4); output layout is exactly this order,
        // so the store address is just ((f32x4*)out)[o].
        int t = o;
        const int w4 = t % W4;        t /= W4;
        const int h  = t % H;         t /= H;
        const int d  = t % D;         t /= D;
        const int cc = t % (2 * C);   t /= (2 * C);
        const int b  = t;
        const int w0 = w4 * 4;

        f32x4 v;
        if (cc < C) {
            // left_vol: aligned contiguous read
            const float* src = L + (((b * C + cc) * H + h) * W + w0);
            v = *reinterpret_cast<const f32x4*>(src);
        } else {
            // right_vol: shifted read at w - d (clamped; masked below)
            const float* src = R + (((b * C + (cc - C)) * H + h) * W);
            const int i0 = w0 - d;
            v.x = src[max(i0 + 0, 0)];
            v.y = src[max(i0 + 1, 0)];
            v.z = src[max(i0 + 2, 0)];
            v.w = src[max(i0 + 3, 0)];
        }

        // Mask w < d to zero. Only possible when w0 < d (rare boundary case).
        if (w0 < d) {
            v.x = (w0 + 0 >= d) ? v.x : 0.0f;
            v.y = (w0 + 1 >= d) ? v.y : 0.0f;
            v.z = (w0 + 2 >= d) ? v.z : 0.0f;
            v.w = (w0 + 3 >= d) ? v.w : 0.0f;
        }

        // Streaming write: nontemporal to keep the 755 MB out of L2/L3.
        __builtin_nontemporal_store(v, reinterpret_cast<f32x4*>(out) + o);
    }
}

extern "C" void kernel_launch(void* const* d_in, const int* in_sizes, int n_in,
                              void* d_out, int out_size, void* d_ws, size_t ws_size,
                              hipStream_t stream)
{
    const float* L = (const float*)d_in[0];
    const float* R = (const float*)d_in[1];
    float* out = (float*)d_out;

    const int block = 256;
    const int grid  = 2048;   // 8 blocks/CU on 256 CUs; grid-stride covers the rest
    concat_volume_kernel<<<grid, block, 0, stream>>>(L, R, out);
}